// Round 3
// baseline (37.817 us; speedup 1.0000x reference)
//
#include <hip/hip_runtime.h>

#define RADIUS 5
#define WIN    11
#define WIN2   121
#define KCLS   6
#define HH     128
#define WW     128
#define BB     4
#define NPIX   (HH*WW)
#define TPB    512                  // 4 threads per pixel, 128 px (one row)
#define NBLK   (BB*HH)              // 512 blocks, one image row each
#define LABW   138                  // cols -5..132
#define LABPL  (WIN*LABW)           // 1518 floats per class plane
#define LABSZ  (KCLS*LABPL)         // 9108 floats = 36.4 KB
#define WPAD   65                   // weight tile stride (bank-conflict-free)

__global__ __launch_bounds__(TPB) void ncut_main(
    const float* __restrict__ labels,
    const float* __restrict__ weights,
    float* __restrict__ part) {
  __shared__ float shl[LABSZ];        // label tile, 6 planes of 11 x 138
  __shared__ float shw[128 * WPAD];   // weight chunk: [px][64 taps], pad 65
  __shared__ int   shtab[WIN2];       // o -> oy*LABW+ox
  __shared__ float shred[8 * 12];

  const int tid = threadIdx.x;
  const int blk = blockIdx.x;
  const int b   = blk >> 7;
  const int y0  = blk & (HH - 1);

  if (tid < WIN2) shtab[tid] = (tid / WIN) * LABW + (tid % WIN);

  // ---- stage zero-padded label tile ----
  const float* labB = labels + (size_t)b * KCLS * NPIX;
  for (int idx = tid; idx < LABSZ; idx += TPB) {
    int k  = idx / LABPL;
    int rm = idx - k * LABPL;
    int tr = rm / LABW;
    int tc = rm - tr * LABW;
    int gy = y0 - RADIUS + tr;
    int gx = tc - RADIUS;
    float v = 0.0f;
    if ((unsigned)gy < (unsigned)HH && (unsigned)gx < (unsigned)WW)
      v = labB[((size_t)k * HH + gy) * WW + gx];
    shl[idx] = v;
  }
  __syncthreads();

  const int px = tid >> 2;          // 0..127
  const int q  = tid & 3;           // 0..3
  const float* wB = weights + ((size_t)b * NPIX + (size_t)y0 * WW) * WIN2;

  float wp[KCLS] = {0.f, 0.f, 0.f, 0.f, 0.f, 0.f};
  float wsum = 0.f;

  // ================= chunk 0: taps 0..63, LDS idx = o =================
#pragma unroll
  for (int i = 0; i < 16; ++i) {      // coalesced: each wave reads 256B runs
    int l = tid + i * TPB;
    int p = l >> 6, tp = l & 63;
    shw[p * WPAD + tp] = wB[p * WIN2 + tp];
  }
  __syncthreads();
#pragma unroll
  for (int g = 0; g < 2; ++g) {
#pragma unroll
    for (int j = 0; j < 8; ++j) {
      const int o = g * 32 + 8 * q + j;
      const float w = shw[px * WPAD + o];
      wsum += w;
      const int li = px + shtab[o];
#pragma unroll
      for (int k = 0; k < KCLS; ++k)
        wp[k] += w * shl[li + k * LABPL];
    }
  }
  __syncthreads();                    // all done reading shw

  // ============ chunk 1: taps 57..120, LDS idx = o - 57 ===============
#pragma unroll
  for (int i = 0; i < 16; ++i) {
    int l = tid + i * TPB;
    int p = l >> 6, tp = l & 63;
    shw[p * WPAD + tp] = wB[p * WIN2 + 57 + tp];   // max idx = 127*121+120 ok
  }
  __syncthreads();
#pragma unroll
  for (int j = 0; j < 8; ++j) {       // o = 64..95
    const int o = 64 + 8 * q + j;
    const float w = shw[px * WPAD + (o - 57)];
    wsum += w;
    const int li = px + shtab[o];
#pragma unroll
    for (int k = 0; k < KCLS; ++k)
      wp[k] += w * shl[li + k * LABPL];
  }
#pragma unroll
  for (int j = 0; j < 8; ++j) {       // o = 96..120 (q==3 only j==0)
    const int o = 96 + 8 * q + j;
    if (o <= 120) {
      const float w = shw[px * WPAD + (o - 57)];
      wsum += w;
      const int li = px + shtab[o];
#pragma unroll
      for (int k = 0; k < KCLS; ++k)
        wp[k] += w * shl[li + k * LABPL];
    }
  }

  // ---- reduce across the 4 q-lanes ----
#pragma unroll
  for (int off = 1; off <= 2; off <<= 1) {
    wsum += __shfl_xor(wsum, off);
#pragma unroll
    for (int k = 0; k < KCLS; ++k) wp[k] += __shfl_xor(wp[k], off);
  }

  // ---- num/den per pixel ----
  const int ce = px + RADIUS * LABW + RADIUS;
  float nv[KCLS], dv[KCLS];
#pragma unroll
  for (int k = 0; k < KCLS; ++k) {
    const float p = shl[ce + k * LABPL];
    nv[k] = p * wp[k];
    dv[k] = p * wsum;
  }

  // ---- reduce across the 16 pixels of this wave ----
#pragma unroll
  for (int off = 4; off <= 32; off <<= 1) {
#pragma unroll
    for (int k = 0; k < KCLS; ++k) {
      nv[k] += __shfl_xor(nv[k], off);
      dv[k] += __shfl_xor(dv[k], off);
    }
  }
  const int wave = tid >> 6;
  if ((tid & 63) == 0) {
#pragma unroll
    for (int k = 0; k < KCLS; ++k) {
      shred[wave * 12 + k]     = nv[k];
      shred[wave * 12 + 6 + k] = dv[k];
    }
  }
  __syncthreads();
  if (tid < 12) {
    float s = 0.f;
#pragma unroll
    for (int w = 0; w < 8; ++w) s += shred[w * 12 + tid];
    part[blk * 12 + tid] = s;
  }
}

// ---- final: L = num/den per (b,k); out = K - (1/B) * sum |L| ----
__global__ __launch_bounds__(64) void ncut_final(
    const float* __restrict__ part, float* __restrict__ out) {
  const int t = threadIdx.x;
  float val = 0.f;
  if (t < BB * KCLS) {
    const int b = t / KCLS;
    const int k = t - b * KCLS;
    float num = 0.f, den = 0.f;
    for (int j = 0; j < HH; ++j) {
      const float* p = part + (size_t)(b * HH + j) * 12;
      num += p[k];
      den += p[6 + k];
    }
    val = fabsf(num / den) * (1.0f / BB);
  }
#pragma unroll
  for (int off = 32; off; off >>= 1) val += __shfl_down(val, off);
  if (t == 0) out[0] = (float)KCLS - val;
}

extern "C" void kernel_launch(void* const* d_in, const int* in_sizes, int n_in,
                              void* d_out, int out_size, void* d_ws, size_t ws_size,
                              hipStream_t stream) {
  const float* labels  = (const float*)d_in[0];
  const float* weights = (const float*)d_in[1];
  float* out  = (float*)d_out;
  float* part = (float*)d_ws;      // 512 blocks * 12 floats = 24576 B

  ncut_main<<<NBLK, TPB, 0, stream>>>(labels, weights, part);
  ncut_final<<<1, 64, 0, stream>>>(part, out);
}

// Round 4
// 23.920 us; speedup vs baseline: 1.5810x; 1.5810x over previous
//
#include <hip/hip_runtime.h>

#define RADIUS 5
#define WIN    11
#define WIN2   121
#define KCLS   6
#define HH     128
#define WW     128
#define BB     4
#define NPIX   (HH*WW)
#define TPB    512                  // 4 threads per pixel, 128 px (one row)
#define NBLK   (BB*HH)              // 512 blocks, one image row each
#define LABW   138                  // cols -5..132
#define LABPL  (WIN*LABW)           // 1518 floats per class plane
#define LABSZ  (KCLS*LABPL)         // 9108 floats = 36.4 KB

__global__ __launch_bounds__(TPB) void ncut_main(
    const float* __restrict__ labels,
    const float* __restrict__ weights,
    float* __restrict__ part) {
  __shared__ float shl[LABSZ];      // zero-padded label tile, K x 11 x 138
  __shared__ int   shtab[128];      // o -> oy*LABW+ox
  __shared__ float shred[8 * 12];   // per-wave partials

  const int tid = threadIdx.x;
  const int blk = blockIdx.x;
  const int b   = blk >> 7;
  const int y0  = blk & (HH - 1);

  if (tid < WIN2) shtab[tid] = (tid / WIN) * LABW + (tid % WIN);

  // ---- stage zero-padded label tile ----
  const float* labB = labels + (size_t)b * KCLS * NPIX;
  for (int idx = tid; idx < LABSZ; idx += TPB) {
    int k  = idx / LABPL;
    int rm = idx - k * LABPL;
    int tr = rm / LABW;
    int tc = rm - tr * LABW;
    int gy = y0 - RADIUS + tr;
    int gx = tc - RADIUS;
    float v = 0.0f;
    if ((unsigned)gy < (unsigned)HH && (unsigned)gx < (unsigned)WW)
      v = labB[((size_t)k * HH + gy) * WW + gx];
    shl[idx] = v;
  }
  __syncthreads();

  // ---- per-thread: pixel px, interleaved tap set o = 4j + q ----
  const int px = tid >> 2;          // 0..127
  const int q  = tid & 3;           // 0..3
  // per-instruction: 4 q-lanes read 4 CONSECUTIVE dwords -> ~1 line per px
  const float* wrowq = weights +
      ((size_t)b * NPIX + (size_t)y0 * WW + px) * WIN2 + q;

  float wp[KCLS] = {0.f, 0.f, 0.f, 0.f, 0.f, 0.f};
  float wsum = 0.f;

#pragma unroll 6
  for (int j = 0; j < 30; ++j) {
    const float w = wrowq[4 * j];           // tap o = 4j + q
    wsum += w;
    const int li = px + shtab[4 * j + q];
#pragma unroll
    for (int k = 0; k < KCLS; ++k)
      wp[k] += w * shl[li + k * LABPL];
  }
  if (q == 0) {                     // tail: o = 120
    const float w = wrowq[120];
    wsum += w;
    const int li = px + shtab[120];
#pragma unroll
    for (int k = 0; k < KCLS; ++k)
      wp[k] += w * shl[li + k * LABPL];
  }

  // ---- reduce across the 4 q-lanes (adjacent lanes) ----
#pragma unroll
  for (int off = 1; off <= 2; off <<= 1) {
    wsum += __shfl_xor(wsum, off);
#pragma unroll
    for (int k = 0; k < KCLS; ++k) wp[k] += __shfl_xor(wp[k], off);
  }

  // ---- num/den per pixel (all 4 q-lanes hold identical values) ----
  const int ce = px + RADIUS * LABW + RADIUS;   // center offset
  float nv[KCLS], dv[KCLS];
#pragma unroll
  for (int k = 0; k < KCLS; ++k) {
    const float p = shl[ce + k * LABPL];
    nv[k] = p * wp[k];
    dv[k] = p * wsum;
  }

  // ---- reduce across the 16 pixels of this wave (lane bits 2..5) ----
#pragma unroll
  for (int off = 4; off <= 32; off <<= 1) {
#pragma unroll
    for (int k = 0; k < KCLS; ++k) {
      nv[k] += __shfl_xor(nv[k], off);
      dv[k] += __shfl_xor(dv[k], off);
    }
  }
  const int wave = tid >> 6;
  if ((tid & 63) == 0) {
#pragma unroll
    for (int k = 0; k < KCLS; ++k) {
      shred[wave * 12 + k]     = nv[k];
      shred[wave * 12 + 6 + k] = dv[k];
    }
  }
  __syncthreads();
  if (tid < 12) {
    float s = 0.f;
#pragma unroll
    for (int w = 0; w < 8; ++w) s += shred[w * 12 + tid];
    part[blk * 12 + tid] = s;
  }
}

// ---- final: L = num/den per (b,k); out = K - (1/B) * sum |L| ----
// segmented: 8 segments x 32 (b,k)-slots, 16 rows each, LDS reduce.
__global__ __launch_bounds__(256) void ncut_final(
    const float* __restrict__ part, float* __restrict__ out) {
  __shared__ float shf[8 * 48];
  const int t   = threadIdx.x;
  const int seg = t >> 5;           // 0..7
  const int bk  = t & 31;           // 0..31, active < 24
  float num = 0.f, den = 0.f;
  if (bk < 24) {
    const int b = bk / KCLS;
    const int k = bk - b * KCLS;
    const int r0 = b * HH + seg * 16;
#pragma unroll 4
    for (int i = 0; i < 16; ++i) {
      const float* p = part + (size_t)(r0 + i) * 12;
      num += p[k];
      den += p[6 + k];
    }
    shf[seg * 48 + bk * 2]     = num;
    shf[seg * 48 + bk * 2 + 1] = den;
  }
  __syncthreads();
  float val = 0.f;
  if (t < 24) {
    float n = 0.f, d = 0.f;
#pragma unroll
    for (int s = 0; s < 8; ++s) {
      n += shf[s * 48 + t * 2];
      d += shf[s * 48 + t * 2 + 1];
    }
    val = fabsf(n / d) * (1.0f / BB);
  }
  if (t < 64) {
#pragma unroll
    for (int off = 16; off; off >>= 1) val += __shfl_down(val, off);
    if (t == 0) out[0] = (float)KCLS - val;
  }
}

extern "C" void kernel_launch(void* const* d_in, const int* in_sizes, int n_in,
                              void* d_out, int out_size, void* d_ws, size_t ws_size,
                              hipStream_t stream) {
  const float* labels  = (const float*)d_in[0];
  const float* weights = (const float*)d_in[1];
  float* out  = (float*)d_out;
  float* part = (float*)d_ws;      // 512 blocks * 12 floats = 24576 B

  ncut_main<<<NBLK, TPB, 0, stream>>>(labels, weights, part);
  ncut_final<<<1, 256, 0, stream>>>(part, out);
}